// Round 10
// baseline (186.009 us; speedup 1.0000x reference)
//
#include <hip/hip_runtime.h>
#include <hip/hip_bf16.h>

#define BB   4
#define NN   8192
#define EE   65536
#define FOBS 128
#define FH   256
#define FOUT 1024
#define NLOG 18
#define BKT  64

typedef __attribute__((ext_vector_type(8))) short frag8;
typedef __attribute__((ext_vector_type(4))) float f32x4;

__device__ __forceinline__ ushort f2b(float v) {
    __hip_bfloat16 h = __float2bfloat16(v);
    return *reinterpret_cast<ushort*>(&h);
}
__device__ __forceinline__ float blo(uint u) { return __uint_as_float(u << 16); }
__device__ __forceinline__ float bhi(uint u) { return __uint_as_float(u & 0xffff0000u); }

// async global->LDS, 16B per lane; LDS dest is wave-uniform base + lane*16
__device__ __forceinline__ void gld16(const void* g, void* l) {
    __builtin_amdgcn_global_load_lds(
        (const __attribute__((address_space(1))) unsigned*)g,
        (__attribute__((address_space(3))) unsigned*)l, 16, 0, 0);
}

// ---------------- prep: x->bf16 + weight transposes + heads pack + cursor + out init ----------------
#define XB2_N  (BB * NN * FOBS / 2)
#define W0_N   (FOBS * FH)
#define W1_N   (FH * FOUT)
#define WH_N   (19 * FOUT)
#define CUR_N  (BB * NN)
#define OUTI_N (BB * NN * 19)
#define PREP_TOTAL (XB2_N + W0_N + W1_N + WH_N + CUR_N + OUTI_N)

__global__ void prep_kernel(const float* __restrict__ nodes, uint* __restrict__ xb,
                            const float* __restrict__ W0, ushort* __restrict__ W0T,
                            const float* __restrict__ W1, ushort* __restrict__ W1T,
                            const float* __restrict__ Wl, const float* __restrict__ Wv,
                            ushort* __restrict__ WT19, int* __restrict__ cursor,
                            const float* __restrict__ bl, const float* __restrict__ bv,
                            float* __restrict__ out_logits, float* __restrict__ out_values) {
    int idx = blockIdx.x * blockDim.x + threadIdx.x;
    if (idx < XB2_N) {
        float2 xx = ((const float2*)nodes)[idx];
        xb[idx] = (uint)f2b(xx.x) | ((uint)f2b(xx.y) << 16);
        return;
    }
    idx -= XB2_N;
    if (idx < W0_N) {
        int n = idx / FOBS, k = idx - n * FOBS;
        W0T[idx] = f2b(W0[(size_t)k * FH + n]);
        return;
    }
    idx -= W0_N;
    if (idx < W1_N) {
        int n = idx / FH, k = idx - n * FH;
        W1T[idx] = f2b(W1[(size_t)k * FOUT + n]);
        return;
    }
    idx -= W1_N;
    if (idx < WH_N) {
        int o = idx >> 10, k = idx & (FOUT - 1);
        WT19[idx] = f2b((o < NLOG) ? Wl[(size_t)k * NLOG + o] : Wv[k]);
        return;
    }
    idx -= WH_N;
    if (idx < CUR_N) { cursor[idx] = 0; return; }
    idx -= CUR_N;
    if (idx < OUTI_N) {
        int gn = idx / 19, o = idx - gn * 19;
        if (o < NLOG) out_logits[(size_t)gn * NLOG + o] = bl[o];
        else          out_values[gn] = bv[0];
    }
}

// ---------------- bucket fill: direct atomic slot allocation, ushort slots ----------------
__global__ void bucket_fill(const int* __restrict__ edges, int* __restrict__ cursor,
                            ushort* __restrict__ bucket) {
    int blk = blockIdx.x;
    int xcd = blk & 7;
    int g = xcd >> 1;
    int chunk = (blk >> 3) * 2 + (xcd & 1);
    int e = chunk * 256 + threadIdx.x;
    const int* src = edges + (size_t)g * 2 * EE;
    const int* dst = src + EE;
    int d = dst[e];
    int slot = atomicAdd(&cursor[(size_t)g * NN + d], 1);
    if (slot < BKT) bucket[((size_t)g * NN + d) * BKT + slot] = (ushort)src[e];
}

// ---------------- gather 1: quarter-wave rows (16 lanes x 16B = 256B bf16 row) ----------------
__global__ __launch_bounds__(256) void gather_agg_b128(
    const uint4* __restrict__ xb4_all, const int* __restrict__ cnt_all,
    const ushort* __restrict__ bucket, uint4* __restrict__ agg_all)
{
    int blk = blockIdx.x;
    int xcd = blk & 7;
    int g = xcd >> 1;
    int chunk = (blk >> 3) * 2 + (xcd & 1);
    int wv = threadIdx.x >> 6, lane = threadIdx.x & 63;
    int n = chunk * 4 + wv;
    int q = lane >> 4, sub = lane & 15;
    const uint4* xb4 = xb4_all + (size_t)g * NN * 16;
    const int* cnt = cnt_all + (size_t)g * NN;
    const ushort* bkt = bucket + ((size_t)g * NN + n) * BKT;

    int cn = cnt[n];
    float wn = rsqrtf((float)cn + 1.0f);
    int total = min(cn, BKT) + 1;        // virtual rows: 0 = self, 1..deg = bucket

    float acc[8] = {};
    for (int base = 0; base < total; base += 8) {
#pragma unroll
        for (int j = 0; j < 2; ++j) {
            int vr = base + q + 4 * j;
            bool ok = vr < total;
            int src = (!ok || vr == 0) ? n : (int)bkt[vr - 1];
            float w = ok ? rsqrtf((float)cnt[src] + 1.0f) * wn : 0.0f;
            uint4 r = xb4[(size_t)src * 16 + sub];
            acc[0] += w * blo(r.x); acc[1] += w * bhi(r.x);
            acc[2] += w * blo(r.y); acc[3] += w * bhi(r.y);
            acc[4] += w * blo(r.z); acc[5] += w * bhi(r.z);
            acc[6] += w * blo(r.w); acc[7] += w * bhi(r.w);
        }
    }
#pragma unroll
    for (int e = 0; e < 8; ++e) {
        acc[e] += __shfl_xor(acc[e], 16);
        acc[e] += __shfl_xor(acc[e], 32);
    }
    if (lane < 16) {
        uint4 o;
        o.x = (uint)f2b(acc[0]) | ((uint)f2b(acc[1]) << 16);
        o.y = (uint)f2b(acc[2]) | ((uint)f2b(acc[3]) << 16);
        o.z = (uint)f2b(acc[4]) | ((uint)f2b(acc[5]) << 16);
        o.w = (uint)f2b(acc[6]) | ((uint)f2b(acc[7]) << 16);
        agg_all[((size_t)g * NN + n) * 16 + sub] = o;
    }
}

// ---------------- gather 2: half-wave rows (32 lanes x 16B = 512B bf16 row) ----------------
__global__ __launch_bounds__(256) void gather_agg_b256(
    const uint4* __restrict__ xb4_all, const int* __restrict__ cnt_all,
    const ushort* __restrict__ bucket, uint4* __restrict__ agg_all)
{
    int blk = blockIdx.x;
    int xcd = blk & 7;
    int g = xcd >> 1;
    int chunk = (blk >> 3) * 2 + (xcd & 1);
    int wv = threadIdx.x >> 6, lane = threadIdx.x & 63;
    int n = chunk * 4 + wv;
    int h = lane >> 5, sub = lane & 31;
    const uint4* xb4 = xb4_all + (size_t)g * NN * 32;
    const int* cnt = cnt_all + (size_t)g * NN;
    const ushort* bkt = bucket + ((size_t)g * NN + n) * BKT;

    int cn = cnt[n];
    float wn = rsqrtf((float)cn + 1.0f);
    int total = min(cn, BKT) + 1;

    float acc[8] = {};
    for (int base = 0; base < total; base += 8) {
#pragma unroll
        for (int j = 0; j < 4; ++j) {
            int vr = base + h + 2 * j;
            bool ok = vr < total;
            int src = (!ok || vr == 0) ? n : (int)bkt[vr - 1];
            float w = ok ? rsqrtf((float)cnt[src] + 1.0f) * wn : 0.0f;
            uint4 r = xb4[(size_t)src * 32 + sub];
            acc[0] += w * blo(r.x); acc[1] += w * bhi(r.x);
            acc[2] += w * blo(r.y); acc[3] += w * bhi(r.y);
            acc[4] += w * blo(r.z); acc[5] += w * bhi(r.z);
            acc[6] += w * blo(r.w); acc[7] += w * bhi(r.w);
        }
    }
#pragma unroll
    for (int e = 0; e < 8; ++e)
        acc[e] += __shfl_xor(acc[e], 32);
    if (lane < 32) {
        uint4 o;
        o.x = (uint)f2b(acc[0]) | ((uint)f2b(acc[1]) << 16);
        o.y = (uint)f2b(acc[2]) | ((uint)f2b(acc[3]) << 16);
        o.z = (uint)f2b(acc[4]) | ((uint)f2b(acc[5]) << 16);
        o.w = (uint)f2b(acc[6]) | ((uint)f2b(acc[7]) << 16);
        agg_all[((size_t)g * NN + n) * 32 + sub] = o;
    }
}

// ---------------- MFMA GEMM (layer 1): T3-minimum double-buffered K-loop ----------------
// stage(next) issued BEFORE ds_read+MFMA(current); single barrier per K-step.
__global__ __launch_bounds__(256) void mfma_gemm(
    const ushort* __restrict__ A_all, const ushort* __restrict__ BT,
    const float* __restrict__ bias, ushort* __restrict__ C_all,
    int M, int N, int K, int relu)
{
    __shared__ __align__(16) char As[2][16384];
    __shared__ __align__(16) char Bs[2][16384];

    int g = blockIdx.z;
    const ushort* A = A_all + (size_t)g * M * K;
    ushort* C = C_all + (size_t)g * M * N;

    int t = threadIdx.x;
    int bn = blockIdx.x, bm = blockIdx.y;
    int lane = t & 63, w = t >> 6;
    int wm = w >> 1, wn = w & 1;
    int l15 = lane & 15, quad = lane >> 4;

    f32x4 acc[4][4] = {};

    const char* Abase = (const char*)(A + (size_t)(bm * 128) * K);
    const char* Bbase = (const char*)(BT + (size_t)(bn * 128) * K);
    size_t rstride = (size_t)K * 2;

    int rsub = lane >> 3;
    int colb = (lane & 7) * 16;

#define G1_STAGE(buf, k0v)                                                        \
    {                                                                             \
        _Pragma("unroll")                                                         \
        for (int c = 0; c < 4; ++c) {                                             \
            int grp = c * 4 + w;                                                  \
            int row = grp * 8 + rsub;                                             \
            int gcol = (k0v) * 2 + (colb ^ ((row & 7) << 4));                     \
            gld16(Abase + (size_t)row * rstride + gcol, As[buf] + grp * 1024);    \
            gld16(Bbase + (size_t)row * rstride + gcol, Bs[buf] + grp * 1024);    \
        }                                                                         \
    }

    G1_STAGE(0, 0);
    __syncthreads();

    int nsteps = K >> 6;
    for (int s = 0; s < nsteps; ++s) {
        if (s + 1 < nsteps) G1_STAGE((s + 1) & 1, (s + 1) * 64);
        const char* Ab = As[s & 1];
        const char* Bb = Bs[s & 1];
#pragma unroll
        for (int kk = 0; kk < 64; kk += 32) {
            frag8 af[4], bf[4];
#pragma unroll
            for (int i = 0; i < 4; ++i) {
                int r = wm * 64 + i * 16 + l15;
                int cb = (kk * 2 + quad * 16) ^ ((r & 7) << 4);
                af[i] = *(const frag8*)(Ab + r * 128 + cb);
            }
#pragma unroll
            for (int j = 0; j < 4; ++j) {
                int r = wn * 64 + j * 16 + l15;
                int cb = (kk * 2 + quad * 16) ^ ((r & 7) << 4);
                bf[j] = *(const frag8*)(Bb + r * 128 + cb);
            }
#pragma unroll
            for (int i = 0; i < 4; ++i)
#pragma unroll
                for (int j = 0; j < 4; ++j)
                    acc[i][j] = __builtin_amdgcn_mfma_f32_16x16x32_bf16(af[i], bf[j], acc[i][j], 0, 0, 0);
        }
        __syncthreads();   // drains this step's prefetch; next buffer ready
    }

#pragma unroll
    for (int i = 0; i < 4; ++i) {
#pragma unroll
        for (int j = 0; j < 4; ++j) {
            int col = bn * 128 + wn * 64 + j * 16 + l15;
            float bcol = bias[col];
#pragma unroll
            for (int r = 0; r < 4; ++r) {
                int row = bm * 128 + wm * 64 + i * 16 + quad * 4 + r;
                float v = acc[i][j][r] + bcol;
                if (relu) v = fmaxf(v, 0.0f);
                C[(size_t)row * N + col] = f2b(v);
            }
        }
    }
}

// ---------------- fused layer-2 GEMM + heads: T3-minimum ping-pong over 16 steps ----------------
// P0 = dedicated 32KB; P1 aliases the Ct region (Ct live only between a bn's last K-step
// and its heads phase; prefetch into P1 never overlaps that window).
// NOTE: buffer selection via runtime ternary — an initialized array of LDS pointers
// triggers an unsupported addrspacecast static initializer on gfx950 (round-9 failure).
__global__ __launch_bounds__(256) void gemm2_heads(
    const ushort* __restrict__ hagg_all,  // [g][NN][FH] bf16
    const ushort* __restrict__ W1T,       // [FOUT][FH] bf16
    const float*  __restrict__ b1,        // [FOUT]
    const ushort* __restrict__ WT19,      // [19][FOUT] bf16
    float* __restrict__ out_logits,       // [B,N,18] f32, pre-init with bias
    float* __restrict__ out_values)       // [B,N]    f32, pre-init with bias
{
    __shared__ __align__(16) ushort smem[128 * 136];     // Ct home; first 32KB doubles as P1
    __shared__ __align__(16) char pbuf0[32768];          // P0
    __shared__ __align__(16) ushort wt[20][136];         // WT19 slice, row19=0

    ushort* Ct = smem;                                   // [128][136]

    int bm = blockIdx.x, sp = blockIdx.y, g = blockIdx.z;
    int t = threadIdx.x;
    int lane = t & 63, w = t >> 6;
    int wm = w >> 1, wn = w & 1;
    int l15 = lane & 15, quad = lane >> 4;
    int rsub = lane >> 3;
    int colb = (lane & 7) * 16;

    const char* A0 = (const char*)(hagg_all + ((size_t)g * NN + bm * 128) * FH);

    // step s (0..15): bn = sp*4 + (s>>2), k0 = (s&3)*64
#define G2_STAGE(dst, sv)                                                          \
    {                                                                              \
        char* Pb_ = (dst);                                                         \
        int bn_ = sp * 4 + ((sv) >> 2);                                            \
        int k0_ = ((sv) & 3) * 64;                                                 \
        const char* Bb_ = (const char*)(W1T + (size_t)(bn_ * 128) * FH);           \
        _Pragma("unroll")                                                          \
        for (int c = 0; c < 4; ++c) {                                              \
            int grp = c * 4 + w;                                                   \
            int row = grp * 8 + rsub;                                              \
            int gcol = k0_ * 2 + (colb ^ ((row & 7) << 4));                        \
            gld16(A0 + (size_t)row * (FH * 2) + gcol, Pb_ + grp * 1024);           \
            gld16(Bb_ + (size_t)row * (FH * 2) + gcol, Pb_ + 16384 + grp * 1024);  \
        }                                                                          \
    }

    if (t < 136) wt[19][t] = 0;
    G2_STAGE(pbuf0, 0);
    __syncthreads();

    f32x4 hacc[2][2] = {};
    f32x4 acc[4][4] = {};

    for (int s = 0; s < 16; ++s) {
        int bi = s >> 2, k0i = s & 3;
        int bn = sp * 4 + bi;

        if (k0i == 0) {
            // stage head-weight slice for this bn (prior heads reads ended at a barrier)
            for (int idx = t; idx < 19 * 16; idx += 256) {
                int row = idx >> 4, c8 = (idx & 15) * 8;
                *(uint4*)&wt[row][c8] = *(const uint4*)(WT19 + (size_t)row * FOUT + bn * 128 + c8);
            }
        }
        if (s < 15) {
            char* nb = ((s + 1) & 1) ? (char*)smem : pbuf0;
            G2_STAGE(nb, s + 1);   // issue next chunk early
        }

        const char* Ab = (s & 1) ? (const char*)smem : (const char*)pbuf0;
        const char* Bb = Ab + 16384;
#pragma unroll
        for (int kk = 0; kk < 64; kk += 32) {
            frag8 af[4], bf[4];
#pragma unroll
            for (int i = 0; i < 4; ++i) {
                int r = wm * 64 + i * 16 + l15;
                int cb = (kk * 2 + quad * 16) ^ ((r & 7) << 4);
                af[i] = *(const frag8*)(Ab + r * 128 + cb);
            }
#pragma unroll
            for (int j = 0; j < 4; ++j) {
                int r = wn * 64 + j * 16 + l15;
                int cb = (kk * 2 + quad * 16) ^ ((r & 7) << 4);
                bf[j] = *(const frag8*)(Bb + r * 128 + cb);
            }
#pragma unroll
            for (int i = 0; i < 4; ++i)
#pragma unroll
                for (int j = 0; j < 4; ++j)
                    acc[i][j] = __builtin_amdgcn_mfma_f32_16x16x32_bf16(af[i], bf[j], acc[i][j], 0, 0, 0);
        }
        __syncthreads();   // drains prefetch + syncs buffer handoff

        if (k0i == 3) {
            // h2 tile -> Ct (bias + relu + bf16); overwrites P1 region (safe: this step's
            // ds_reads are done, and the in-flight prefetch targets P0)
#pragma unroll
            for (int j = 0; j < 4; ++j) {
                int colL = wn * 64 + j * 16 + l15;
                float bcol = b1[bn * 128 + colL];
#pragma unroll
                for (int i = 0; i < 4; ++i) {
                    int rowL = wm * 64 + i * 16 + quad * 4;
#pragma unroll
                    for (int r = 0; r < 4; ++r) {
                        float v = fmaxf(acc[i][j][r] + bcol, 0.0f);
                        Ct[(size_t)(rowL + r) * 136 + colL] = f2b(v);
                    }
                }
            }
#pragma unroll
            for (int i = 0; i < 4; ++i)
#pragma unroll
                for (int j = 0; j < 4; ++j)
                    acc[i][j] = f32x4{0.f, 0.f, 0.f, 0.f};
            __syncthreads();

            int r1 = (l15 < 3) ? (16 + l15) : 19;
#pragma unroll
            for (int kk = 0; kk < 128; kk += 32) {
                frag8 b0 = *(const frag8*)&wt[l15][kk + quad * 8];
                frag8 bO = *(const frag8*)&wt[r1][kk + quad * 8];
#pragma unroll
                for (int mt = 0; mt < 2; ++mt) {
                    int row = (w * 2 + mt) * 16 + l15;
                    frag8 af = *(const frag8*)&Ct[(size_t)row * 136 + kk + quad * 8];
                    hacc[mt][0] = __builtin_amdgcn_mfma_f32_16x16x32_bf16(af, b0, hacc[mt][0], 0, 0, 0);
                    hacc[mt][1] = __builtin_amdgcn_mfma_f32_16x16x32_bf16(af, bO, hacc[mt][1], 0, 0, 0);
                }
            }
            __syncthreads();   // heads done with Ct/wt before next bn's wt staging / P1 prefetch
        }
    }

#pragma unroll
    for (int mt = 0; mt < 2; ++mt) {
#pragma unroll
        for (int r = 0; r < 4; ++r) {
            int node = bm * 128 + (w * 2 + mt) * 16 + quad * 4 + r;
            size_t gn = (size_t)g * NN + node;
            atomicAdd(&out_logits[gn * NLOG + l15], hacc[mt][0][r]);
            if (l15 < 2)       atomicAdd(&out_logits[gn * NLOG + 16 + l15], hacc[mt][1][r]);
            else if (l15 == 2) atomicAdd(&out_values[gn], hacc[mt][1][r]);
        }
    }
}

// ---------------- launcher ----------------
extern "C" void kernel_launch(void* const* d_in, const int* in_sizes, int n_in,
                              void* d_out, int out_size, void* d_ws, size_t ws_size,
                              hipStream_t stream) {
    const float* nodes = (const float*)d_in[0];
    const int*   edges = (const int*)d_in[1];
    const float* W0 = (const float*)d_in[2];
    const float* b0 = (const float*)d_in[3];
    const float* W1 = (const float*)d_in[4];
    const float* b1 = (const float*)d_in[5];
    const float* Wl = (const float*)d_in[6];
    const float* bl = (const float*)d_in[7];
    const float* Wv = (const float*)d_in[8];
    const float* bv = (const float*)d_in[9];

    float* out_logits = (float*)d_out;
    float* out_values = out_logits + (size_t)BB * NN * NLOG;

    char* ws = (char*)d_ws;
    int*    cursor  = (int*)(ws);                     // 128 KB (becomes cnt)
    ushort* W0T     = (ushort*)(ws + (128 << 10));    // 64 KB
    ushort* W1T     = (ushort*)(ws + (192 << 10));    // 512 KB
    ushort* WT19    = (ushort*)(ws + (704 << 10));    // 38 KB
    uint*   xb      = (uint*)(ws + (1u << 20));       // 8 MB   [B,N,128] bf16
    ushort* bucket  = (ushort*)(ws + (9u << 20));     // 4 MB   [B,N,64] ushort
    ushort* xagg_b  = (ushort*)(ws + (13u << 20));    // 8 MB   [B,N,128] bf16
    ushort* h1b     = (ushort*)(ws + (21u << 20));    // 16 MB  [B,N,256] bf16
    ushort* hagg_b  = (ushort*)(ws + (37u << 20));    // 16 MB  [B,N,256] bf16
    // total ~53 MB

    // 1. prep (x->bf16, weight transposes, cursor zero, out bias-init)
    prep_kernel<<<(PREP_TOTAL + 255) / 256, 256, 0, stream>>>(
        nodes, xb, W0, W0T, W1, W1T, Wl, Wv, WT19, cursor, bl, bv, out_logits, out_values);

    // 2. bucket fill (ushort slots)
    bucket_fill<<<1024, 256, 0, stream>>>(edges, cursor, bucket);

    // 3. layer-1 aggregation (quarter-wave 16B rows)
    gather_agg_b128<<<(NN / 4) * BB, 256, 0, stream>>>((const uint4*)xb, cursor, bucket,
                                                       (uint4*)xagg_b);

    // 4. layer-1 GEMM (T3-minimum pipelined)
    mfma_gemm<<<dim3(FH / 128, NN / 128, BB), 256, 0, stream>>>(
        xagg_b, W0T, b0, h1b, NN, FH, FOBS, 1);

    // 5. layer-2 aggregation (half-wave 16B rows)
    gather_agg_b256<<<(NN / 4) * BB, 256, 0, stream>>>((const uint4*)h1b, cursor, bucket,
                                                       (uint4*)hagg_b);

    // 6. fused layer-2 GEMM + heads (T3-minimum ping-pong, atomic combine into d_out)
    gemm2_heads<<<dim3(NN / 128, 2, BB), 256, 0, stream>>>(hagg_b, W1T, b1, WT19,
                                                           out_logits, out_values);
}

// Round 11
// 180.958 us; speedup vs baseline: 1.0279x; 1.0279x over previous
//
#include <hip/hip_runtime.h>
#include <hip/hip_bf16.h>

#define BB   4
#define NN   8192
#define EE   65536
#define FOBS 128
#define FH   256
#define FOUT 1024
#define NLOG 18
#define BKT  64

typedef __attribute__((ext_vector_type(8))) short frag8;
typedef __attribute__((ext_vector_type(4))) float f32x4;

__device__ __forceinline__ ushort f2b(float v) {
    __hip_bfloat16 h = __float2bfloat16(v);
    return *reinterpret_cast<ushort*>(&h);
}
__device__ __forceinline__ float blo(uint u) { return __uint_as_float(u << 16); }
__device__ __forceinline__ float bhi(uint u) { return __uint_as_float(u & 0xffff0000u); }

// async global->LDS, 16B per lane; LDS dest is wave-uniform base + lane*16
__device__ __forceinline__ void gld16(const void* g, void* l) {
    __builtin_amdgcn_global_load_lds(
        (const __attribute__((address_space(1))) unsigned*)g,
        (__attribute__((address_space(3))) unsigned*)l, 16, 0, 0);
}

// ---------------- prep: x->bf16 (float4-wide) + weight transposes + heads pack + cursor + out init ----------------
#define XB4_N  (BB * NN * FOBS / 4)
#define W0_N   (FOBS * FH)
#define W1_N   (FH * FOUT)
#define WH_N   (19 * FOUT)
#define CUR_N  (BB * NN)
#define OUTI_N (BB * NN * 19)
#define PREP_TOTAL (XB4_N + W0_N + W1_N + WH_N + CUR_N + OUTI_N)

__global__ void prep_kernel(const float* __restrict__ nodes, uint* __restrict__ xb,
                            const float* __restrict__ W0, ushort* __restrict__ W0T,
                            const float* __restrict__ W1, ushort* __restrict__ W1T,
                            const float* __restrict__ Wl, const float* __restrict__ Wv,
                            ushort* __restrict__ WT19, int* __restrict__ cursor,
                            const float* __restrict__ bl, const float* __restrict__ bv,
                            float* __restrict__ out_logits, float* __restrict__ out_values) {
    int idx = blockIdx.x * blockDim.x + threadIdx.x;
    if (idx < XB4_N) {
        float4 xx = ((const float4*)nodes)[idx];
        uint2 o;
        o.x = (uint)f2b(xx.x) | ((uint)f2b(xx.y) << 16);
        o.y = (uint)f2b(xx.z) | ((uint)f2b(xx.w) << 16);
        ((uint2*)xb)[idx] = o;
        return;
    }
    idx -= XB4_N;
    if (idx < W0_N) {
        int n = idx / FOBS, k = idx - n * FOBS;
        W0T[idx] = f2b(W0[(size_t)k * FH + n]);
        return;
    }
    idx -= W0_N;
    if (idx < W1_N) {
        int n = idx / FH, k = idx - n * FH;
        W1T[idx] = f2b(W1[(size_t)k * FOUT + n]);
        return;
    }
    idx -= W1_N;
    if (idx < WH_N) {
        int o = idx >> 10, k = idx & (FOUT - 1);
        WT19[idx] = f2b((o < NLOG) ? Wl[(size_t)k * NLOG + o] : Wv[k]);
        return;
    }
    idx -= WH_N;
    if (idx < CUR_N) { cursor[idx] = 0; return; }
    idx -= CUR_N;
    if (idx < OUTI_N) {
        int gn = idx / 19, o = idx - gn * 19;
        if (o < NLOG) out_logits[(size_t)gn * NLOG + o] = bl[o];
        else          out_values[gn] = bv[0];
    }
}

// ---------------- bucket fill: direct atomic slot allocation, ushort slots ----------------
__global__ void bucket_fill(const int* __restrict__ edges, int* __restrict__ cursor,
                            ushort* __restrict__ bucket) {
    int blk = blockIdx.x;
    int xcd = blk & 7;
    int g = xcd >> 1;
    int chunk = (blk >> 3) * 2 + (xcd & 1);
    int e = chunk * 256 + threadIdx.x;
    const int* src = edges + (size_t)g * 2 * EE;
    const int* dst = src + EE;
    int d = dst[e];
    int slot = atomicAdd(&cursor[(size_t)g * NN + d], 1);
    if (slot < BKT) bucket[((size_t)g * NN + d) * BKT + slot] = (ushort)src[e];
}

// ---------------- gather 1: quarter-wave rows (16 lanes x 16B = 256B bf16 row) ----------------
__global__ __launch_bounds__(256) void gather_agg_b128(
    const uint4* __restrict__ xb4_all, const int* __restrict__ cnt_all,
    const ushort* __restrict__ bucket, uint4* __restrict__ agg_all)
{
    int blk = blockIdx.x;
    int xcd = blk & 7;
    int g = xcd >> 1;
    int chunk = (blk >> 3) * 2 + (xcd & 1);
    int wv = threadIdx.x >> 6, lane = threadIdx.x & 63;
    int n = chunk * 4 + wv;
    int q = lane >> 4, sub = lane & 15;
    const uint4* xb4 = xb4_all + (size_t)g * NN * 16;
    const int* cnt = cnt_all + (size_t)g * NN;
    const ushort* bkt = bucket + ((size_t)g * NN + n) * BKT;

    int cn = cnt[n];
    float wn = rsqrtf((float)cn + 1.0f);
    int total = min(cn, BKT) + 1;        // virtual rows: 0 = self, 1..deg = bucket

    float acc[8] = {};
    for (int base = 0; base < total; base += 8) {
#pragma unroll
        for (int j = 0; j < 2; ++j) {
            int vr = base + q + 4 * j;
            bool ok = vr < total;
            int src = (!ok || vr == 0) ? n : (int)bkt[vr - 1];
            float w = ok ? rsqrtf((float)cnt[src] + 1.0f) * wn : 0.0f;
            uint4 r = xb4[(size_t)src * 16 + sub];
            acc[0] += w * blo(r.x); acc[1] += w * bhi(r.x);
            acc[2] += w * blo(r.y); acc[3] += w * bhi(r.y);
            acc[4] += w * blo(r.z); acc[5] += w * bhi(r.z);
            acc[6] += w * blo(r.w); acc[7] += w * bhi(r.w);
        }
    }
#pragma unroll
    for (int e = 0; e < 8; ++e) {
        acc[e] += __shfl_xor(acc[e], 16);
        acc[e] += __shfl_xor(acc[e], 32);
    }
    if (lane < 16) {
        uint4 o;
        o.x = (uint)f2b(acc[0]) | ((uint)f2b(acc[1]) << 16);
        o.y = (uint)f2b(acc[2]) | ((uint)f2b(acc[3]) << 16);
        o.z = (uint)f2b(acc[4]) | ((uint)f2b(acc[5]) << 16);
        o.w = (uint)f2b(acc[6]) | ((uint)f2b(acc[7]) << 16);
        agg_all[((size_t)g * NN + n) * 16 + sub] = o;
    }
}

// ---------------- gather 2: half-wave rows (32 lanes x 16B = 512B bf16 row) ----------------
__global__ __launch_bounds__(256) void gather_agg_b256(
    const uint4* __restrict__ xb4_all, const int* __restrict__ cnt_all,
    const ushort* __restrict__ bucket, uint4* __restrict__ agg_all)
{
    int blk = blockIdx.x;
    int xcd = blk & 7;
    int g = xcd >> 1;
    int chunk = (blk >> 3) * 2 + (xcd & 1);
    int wv = threadIdx.x >> 6, lane = threadIdx.x & 63;
    int n = chunk * 4 + wv;
    int h = lane >> 5, sub = lane & 31;
    const uint4* xb4 = xb4_all + (size_t)g * NN * 32;
    const int* cnt = cnt_all + (size_t)g * NN;
    const ushort* bkt = bucket + ((size_t)g * NN + n) * BKT;

    int cn = cnt[n];
    float wn = rsqrtf((float)cn + 1.0f);
    int total = min(cn, BKT) + 1;

    float acc[8] = {};
    for (int base = 0; base < total; base += 8) {
#pragma unroll
        for (int j = 0; j < 4; ++j) {
            int vr = base + h + 2 * j;
            bool ok = vr < total;
            int src = (!ok || vr == 0) ? n : (int)bkt[vr - 1];
            float w = ok ? rsqrtf((float)cnt[src] + 1.0f) * wn : 0.0f;
            uint4 r = xb4[(size_t)src * 32 + sub];
            acc[0] += w * blo(r.x); acc[1] += w * bhi(r.x);
            acc[2] += w * blo(r.y); acc[3] += w * bhi(r.y);
            acc[4] += w * blo(r.z); acc[5] += w * bhi(r.z);
            acc[6] += w * blo(r.w); acc[7] += w * bhi(r.w);
        }
    }
#pragma unroll
    for (int e = 0; e < 8; ++e)
        acc[e] += __shfl_xor(acc[e], 32);
    if (lane < 32) {
        uint4 o;
        o.x = (uint)f2b(acc[0]) | ((uint)f2b(acc[1]) << 16);
        o.y = (uint)f2b(acc[2]) | ((uint)f2b(acc[3]) << 16);
        o.z = (uint)f2b(acc[4]) | ((uint)f2b(acc[5]) << 16);
        o.w = (uint)f2b(acc[6]) | ((uint)f2b(acc[7]) << 16);
        agg_all[((size_t)g * NN + n) * 32 + sub] = o;
    }
}

// ---------------- MFMA GEMM (layer 1): K=128 single-stage, ONE barrier ----------------
// Both 64-wide K-chunks staged up front (16 gld16/lane all in flight), then 64 MFMAs.
__global__ __launch_bounds__(256) void mfma_gemm(
    const ushort* __restrict__ A_all, const ushort* __restrict__ BT,
    const float* __restrict__ bias, ushort* __restrict__ C_all,
    int M, int N, int K, int relu)
{
    __shared__ __align__(16) char As[2][16384];   // chunk ch: k = ch*64 .. ch*64+63
    __shared__ __align__(16) char Bs[2][16384];

    int g = blockIdx.z;
    const ushort* A = A_all + (size_t)g * M * K;
    ushort* C = C_all + (size_t)g * M * N;

    int t = threadIdx.x;
    int bn = blockIdx.x, bm = blockIdx.y;
    int lane = t & 63, w = t >> 6;
    int wm = w >> 1, wn = w & 1;
    int l15 = lane & 15, quad = lane >> 4;

    f32x4 acc[4][4] = {};

    const char* Abase = (const char*)(A + (size_t)(bm * 128) * K);
    const char* Bbase = (const char*)(BT + (size_t)(bn * 128) * K);
    size_t rstride = (size_t)K * 2;

    int rsub = lane >> 3;
    int colb = (lane & 7) * 16;

#pragma unroll
    for (int ch = 0; ch < 2; ++ch) {
#pragma unroll
        for (int c = 0; c < 4; ++c) {
            int grp = c * 4 + w;
            int row = grp * 8 + rsub;
            int gcol = ch * 128 + (colb ^ ((row & 7) << 4));
            gld16(Abase + (size_t)row * rstride + gcol, As[ch] + grp * 1024);
            gld16(Bbase + (size_t)row * rstride + gcol, Bs[ch] + grp * 1024);
        }
    }
    __syncthreads();

#pragma unroll
    for (int ch = 0; ch < 2; ++ch) {
#pragma unroll
        for (int kk = 0; kk < 64; kk += 32) {
            frag8 af[4], bf[4];
#pragma unroll
            for (int i = 0; i < 4; ++i) {
                int r = wm * 64 + i * 16 + l15;
                int cb = (kk * 2 + quad * 16) ^ ((r & 7) << 4);
                af[i] = *(const frag8*)(As[ch] + r * 128 + cb);
            }
#pragma unroll
            for (int j = 0; j < 4; ++j) {
                int r = wn * 64 + j * 16 + l15;
                int cb = (kk * 2 + quad * 16) ^ ((r & 7) << 4);
                bf[j] = *(const frag8*)(Bs[ch] + r * 128 + cb);
            }
#pragma unroll
            for (int i = 0; i < 4; ++i)
#pragma unroll
                for (int j = 0; j < 4; ++j)
                    acc[i][j] = __builtin_amdgcn_mfma_f32_16x16x32_bf16(af[i], bf[j], acc[i][j], 0, 0, 0);
        }
    }

#pragma unroll
    for (int i = 0; i < 4; ++i) {
#pragma unroll
        for (int j = 0; j < 4; ++j) {
            int col = bn * 128 + wn * 64 + j * 16 + l15;
            float bcol = bias[col];
#pragma unroll
            for (int r = 0; r < 4; ++r) {
                int row = bm * 128 + wm * 64 + i * 16 + quad * 4 + r;
                float v = acc[i][j][r] + bcol;
                if (relu) v = fmaxf(v, 0.0f);
                C[(size_t)row * N + col] = f2b(v);
            }
        }
    }
}

// ---------------- fused layer-2 GEMM + heads, atomic combine into d_out (round-8 form) ----------------
__global__ __launch_bounds__(256) void gemm2_heads(
    const ushort* __restrict__ hagg_all,  // [g][NN][FH] bf16
    const ushort* __restrict__ W1T,       // [FOUT][FH] bf16
    const float*  __restrict__ b1,        // [FOUT]
    const ushort* __restrict__ WT19,      // [19][FOUT] bf16
    float* __restrict__ out_logits,       // [B,N,18] f32, pre-init with bias
    float* __restrict__ out_values)       // [B,N]    f32, pre-init with bias
{
    __shared__ __align__(16) ushort smem[128 * 136];     // As|Bs chunks; reused as Ct
    __shared__ __align__(16) ushort wt[20][136];         // WT19 slice, row19=0

    char* AsB = (char*)smem;
    char* BsB = (char*)smem + 16384;
    ushort* Ct = smem;                                   // [128][136]

    int bm = blockIdx.x, sp = blockIdx.y, g = blockIdx.z;
    int t = threadIdx.x;
    int lane = t & 63, w = t >> 6;
    int wm = w >> 1, wn = w & 1;
    int l15 = lane & 15, quad = lane >> 4;

    const char* A0 = (const char*)(hagg_all + ((size_t)g * NN + bm * 128) * FH);

    if (t < 136) wt[19][t] = 0;

    int rsub = lane >> 3;
    int colb = (lane & 7) * 16;

    f32x4 hacc[2][2] = {};

    for (int bi = 0; bi < 4; ++bi) {
        int bn = sp * 4 + bi;
        __syncthreads();   // protects Ct/wt of previous iteration from restaging

        for (int idx = t; idx < 19 * 16; idx += 256) {
            int row = idx >> 4, c8 = (idx & 15) * 8;
            *(uint4*)&wt[row][c8] = *(const uint4*)(WT19 + (size_t)row * FOUT + bn * 128 + c8);
        }

        f32x4 acc[4][4] = {};
        const char* Bbase = (const char*)(W1T + (size_t)(bn * 128) * FH);

        for (int k0 = 0; k0 < FH; k0 += 64) {
#pragma unroll
            for (int c = 0; c < 4; ++c) {
                int grp = c * 4 + w;
                int row = grp * 8 + rsub;
                int gcol = k0 * 2 + (colb ^ ((row & 7) << 4));
                gld16(A0 + (size_t)row * (FH * 2) + gcol, AsB + grp * 1024);
                gld16(Bbase + (size_t)row * (FH * 2) + gcol, BsB + grp * 1024);
            }
            __syncthreads();
#pragma unroll
            for (int kk = 0; kk < 64; kk += 32) {
                frag8 af[4], bf[4];
#pragma unroll
                for (int i = 0; i < 4; ++i) {
                    int r = wm * 64 + i * 16 + l15;
                    int cb = (kk * 2 + quad * 16) ^ ((r & 7) << 4);
                    af[i] = *(const frag8*)(AsB + r * 128 + cb);
                }
#pragma unroll
                for (int j = 0; j < 4; ++j) {
                    int r = wn * 64 + j * 16 + l15;
                    int cb = (kk * 2 + quad * 16) ^ ((r & 7) << 4);
                    bf[j] = *(const frag8*)(BsB + r * 128 + cb);
                }
#pragma unroll
                for (int i = 0; i < 4; ++i)
#pragma unroll
                    for (int j = 0; j < 4; ++j)
                        acc[i][j] = __builtin_amdgcn_mfma_f32_16x16x32_bf16(af[i], bf[j], acc[i][j], 0, 0, 0);
            }
            __syncthreads();
        }

#pragma unroll
        for (int j = 0; j < 4; ++j) {
            int colL = wn * 64 + j * 16 + l15;
            float bcol = b1[bn * 128 + colL];
#pragma unroll
            for (int i = 0; i < 4; ++i) {
                int rowL = wm * 64 + i * 16 + quad * 4;
#pragma unroll
                for (int r = 0; r < 4; ++r) {
                    float v = fmaxf(acc[i][j][r] + bcol, 0.0f);
                    Ct[(size_t)(rowL + r) * 136 + colL] = f2b(v);
                }
            }
        }
        __syncthreads();

        int r1 = (l15 < 3) ? (16 + l15) : 19;
#pragma unroll
        for (int kk = 0; kk < 128; kk += 32) {
            frag8 b0 = *(const frag8*)&wt[l15][kk + quad * 8];
            frag8 bO = *(const frag8*)&wt[r1][kk + quad * 8];
#pragma unroll
            for (int mt = 0; mt < 2; ++mt) {
                int row = (w * 2 + mt) * 16 + l15;
                frag8 af = *(const frag8*)&Ct[(size_t)row * 136 + kk + quad * 8];
                hacc[mt][0] = __builtin_amdgcn_mfma_f32_16x16x32_bf16(af, b0, hacc[mt][0], 0, 0, 0);
                hacc[mt][1] = __builtin_amdgcn_mfma_f32_16x16x32_bf16(af, bO, hacc[mt][1], 0, 0, 0);
            }
        }
    }

#pragma unroll
    for (int mt = 0; mt < 2; ++mt) {
#pragma unroll
        for (int r = 0; r < 4; ++r) {
            int node = bm * 128 + (w * 2 + mt) * 16 + quad * 4 + r;
            size_t gn = (size_t)g * NN + node;
            atomicAdd(&out_logits[gn * NLOG + l15], hacc[mt][0][r]);
            if (l15 < 2)       atomicAdd(&out_logits[gn * NLOG + 16 + l15], hacc[mt][1][r]);
            else if (l15 == 2) atomicAdd(&out_values[gn], hacc[mt][1][r]);
        }
    }
}

// ---------------- launcher ----------------
extern "C" void kernel_launch(void* const* d_in, const int* in_sizes, int n_in,
                              void* d_out, int out_size, void* d_ws, size_t ws_size,
                              hipStream_t stream) {
    const float* nodes = (const float*)d_in[0];
    const int*   edges = (const int*)d_in[1];
    const float* W0 = (const float*)d_in[2];
    const float* b0 = (const float*)d_in[3];
    const float* W1 = (const float*)d_in[4];
    const float* b1 = (const float*)d_in[5];
    const float* Wl = (const float*)d_in[6];
    const float* bl = (const float*)d_in[7];
    const float* Wv = (const float*)d_in[8];
    const float* bv = (const float*)d_in[9];

    float* out_logits = (float*)d_out;
    float* out_values = out_logits + (size_t)BB * NN * NLOG;

    char* ws = (char*)d_ws;
    int*    cursor  = (int*)(ws);                     // 128 KB (becomes cnt)
    ushort* W0T     = (ushort*)(ws + (128 << 10));    // 64 KB
    ushort* W1T     = (ushort*)(ws + (192 << 10));    // 512 KB
    ushort* WT19    = (ushort*)(ws + (704 << 10));    // 38 KB
    uint*   xb      = (uint*)(ws + (1u << 20));       // 8 MB   [B,N,128] bf16
    ushort* bucket  = (ushort*)(ws + (9u << 20));     // 4 MB   [B,N,64] ushort
    ushort* xagg_b  = (ushort*)(ws + (13u << 20));    // 8 MB   [B,N,128] bf16
    ushort* h1b     = (ushort*)(ws + (21u << 20));    // 16 MB  [B,N,256] bf16
    ushort* hagg_b  = (ushort*)(ws + (37u << 20));    // 16 MB  [B,N,256] bf16
    // total ~53 MB

    // 1. prep (x->bf16 float4-wide, weight transposes, cursor zero, out bias-init)
    prep_kernel<<<(PREP_TOTAL + 255) / 256, 256, 0, stream>>>(
        nodes, xb, W0, W0T, W1, W1T, Wl, Wv, WT19, cursor, bl, bv, out_logits, out_values);

    // 2. bucket fill (ushort slots)
    bucket_fill<<<1024, 256, 0, stream>>>(edges, cursor, bucket);

    // 3. layer-1 aggregation (quarter-wave 16B rows)
    gather_agg_b128<<<(NN / 4) * BB, 256, 0, stream>>>((const uint4*)xb, cursor, bucket,
                                                       (uint4*)xagg_b);

    // 4. layer-1 GEMM (single-stage, one barrier)
    mfma_gemm<<<dim3(FH / 128, NN / 128, BB), 256, 0, stream>>>(
        xagg_b, W0T, b0, h1b, NN, FH, FOBS, 1);

    // 5. layer-2 aggregation (half-wave 16B rows)
    gather_agg_b256<<<(NN / 4) * BB, 256, 0, stream>>>((const uint4*)h1b, cursor, bucket,
                                                       (uint4*)hagg_b);

    // 6. fused layer-2 GEMM + heads (round-8 structure, atomic combine into d_out)
    gemm2_heads<<<dim3(NN / 128, 2, BB), 256, 0, stream>>>(hagg_b, W1T, b1, WT19,
                                                           out_logits, out_values);
}